// Round 1
// baseline (4926.367 us; speedup 1.0000x reference)
//
#include <hip/hip_runtime.h>

typedef __attribute__((ext_vector_type(8))) short short8;
typedef __attribute__((ext_vector_type(8))) unsigned short ushort8v;
typedef __attribute__((ext_vector_type(4))) unsigned short ushort4v;
typedef __attribute__((ext_vector_type(4))) float f32x4;

__device__ __forceinline__ unsigned short f2bf(float f) {
  unsigned int u = __float_as_uint(f);
  u += 0x7FFFu + ((u >> 16) & 1u);
  return (unsigned short)(u >> 16);
}

#define TBM 128
#define TBN 128
#define TBK 64
#define LDK 72  // +8 bf16 pad: row stride 144B = 9*16B -> 2-way bank alias (free), b128-aligned

// ---------------- MFMA GEMM: C[M x Npad] = A[M x K] * Bt[Npad x K]^T + bias ----------------
// Bt is pre-transposed [n][k] bf16 (padded, no guards needed on B).
// A is fp32 (A_BF16=0, guarded on M and K) or bf16 (A_BF16=1, guarded on M; K padded).
template<bool A_BF16, bool OUT_BF16>
__global__ __launch_bounds__(256) void gemm_kernel(
    const void* __restrict__ Av, int lda, const unsigned short* __restrict__ Bt,
    int ldb, const float* __restrict__ bias, void* __restrict__ Cv, int ldc,
    int col_off, int M, int K, int ktiles) {
  __shared__ unsigned short As[TBM][LDK];
  __shared__ unsigned short Bs[TBN][LDK];
  const int tid = threadIdx.x;
  const int bm = blockIdx.x * TBM;
  const int bn = blockIdx.y * TBN;
  const int wave = tid >> 6;
  const int lane = tid & 63;
  const int wr = (wave >> 1) * 64;
  const int wc = (wave & 1) * 64;
  const int l15 = lane & 15;
  const int quad = lane >> 4;

  f32x4 acc[4][4];
#pragma unroll
  for (int i = 0; i < 4; i++)
#pragma unroll
    for (int j = 0; j < 4; j++) acc[i][j] = (f32x4){0.f, 0.f, 0.f, 0.f};

  const int arow = tid >> 1;  // 0..127, 2 threads per row
  const int grow = bm + arow;

  for (int kt = 0; kt < ktiles; ++kt) {
    const int k0 = kt * TBK;
    // ---- stage A tile (convert fp32->bf16 if needed) ----
    if (!A_BF16) {
      const float* A = (const float*)Av;
#pragma unroll
      for (int i = 0; i < 8; i++) {
        int c = ((tid & 1) * 8 + i) * 4;
        int gk = k0 + c;
        f32x4 v = (f32x4){0.f, 0.f, 0.f, 0.f};
        if (grow < M && gk < K) v = *(const f32x4*)(A + (size_t)grow * lda + gk);
        ushort4v hv = {f2bf(v[0]), f2bf(v[1]), f2bf(v[2]), f2bf(v[3])};
        *(ushort4v*)&As[arow][c] = hv;
      }
    } else {
      const unsigned short* A = (const unsigned short*)Av;
#pragma unroll
      for (int i = 0; i < 4; i++) {
        int c = ((tid & 1) * 4 + i) * 8;
        ushort8v v = (ushort8v){0, 0, 0, 0, 0, 0, 0, 0};
        if (grow < M) v = *(const ushort8v*)(A + (size_t)grow * lda + k0 + c);
        *(ushort8v*)&As[arow][c] = v;
      }
    }
    // ---- stage B tile (already [n][k], contiguous copy) ----
#pragma unroll
    for (int i = 0; i < 4; i++) {
      int c = ((tid & 1) * 4 + i) * 8;
      ushort8v v = *(const ushort8v*)(Bt + (size_t)(bn + arow) * ldb + k0 + c);
      *(ushort8v*)&Bs[arow][c] = v;
    }
    __syncthreads();
#pragma unroll
    for (int kk = 0; kk < TBK; kk += 32) {
      short8 a[4], b[4];
      const int ks = kk + quad * 8;
#pragma unroll
      for (int i = 0; i < 4; i++) a[i] = *(const short8*)&As[wr + i * 16 + l15][ks];
#pragma unroll
      for (int j = 0; j < 4; j++) b[j] = *(const short8*)&Bs[wc + j * 16 + l15][ks];
#pragma unroll
      for (int i = 0; i < 4; i++)
#pragma unroll
        for (int j = 0; j < 4; j++)
          acc[i][j] = __builtin_amdgcn_mfma_f32_16x16x32_bf16(a[i], b[j], acc[i][j], 0, 0, 0);
    }
    __syncthreads();
  }

  // ---- epilogue: C/D layout col=lane&15, row=quad*4+reg ----
#pragma unroll
  for (int i = 0; i < 4; i++) {
    int rowb = bm + wr + i * 16 + quad * 4;
#pragma unroll
    for (int j = 0; j < 4; j++) {
      int col = bn + wc + j * 16 + l15;
      float bv = bias[col];
#pragma unroll
      for (int r = 0; r < 4; r++) {
        int row = rowb + r;
        if (row < M) {
          float v = acc[i][j][r] + bv;
          if (OUT_BF16)
            ((unsigned short*)Cv)[(size_t)row * ldc + col_off + col] = f2bf(v);
          else
            ((float*)Cv)[(size_t)row * ldc + col_off + col] = v;
        }
      }
    }
  }
}

// ---------------- weight prep: transpose + BN-fold + bf16 + pad ----------------
// W1 [2][2000][500] -> W1T [2][512][2048] bf16 scaled; fb1 [2][512]
__global__ void prep_w1t(const float* __restrict__ W1, const float* __restrict__ b1,
                         const float* __restrict__ g1, const float* __restrict__ be1,
                         const float* __restrict__ m1, const float* __restrict__ v1,
                         unsigned short* __restrict__ W1T, float* __restrict__ fb1) {
  int t = blockIdx.x * blockDim.x + threadIdx.x;
  if (t >= 2 * 512 * 2048) return;
  int k = t & 2047, j = (t >> 11) & 511, m = t >> 20;
  float val = 0.f;
  if (j < 500 && k < 2000) {
    float s = g1[m * 500 + j] * rsqrtf(v1[m * 500 + j] + 1e-5f);
    val = W1[((size_t)m * 2000 + k) * 500 + j] * s;
  }
  W1T[t] = f2bf(val);
  if (k == 0) {
    float bv = 0.f;
    if (j < 500) {
      float s = g1[m * 500 + j] * rsqrtf(v1[m * 500 + j] + 1e-5f);
      bv = (b1[m * 500 + j] - m1[m * 500 + j]) * s + be1[m * 500 + j];
    }
    fb1[m * 512 + j] = bv;
  }
}

// W2 [2][500][128] -> W2T [2][128][512]; fb2 [2][128]
__global__ void prep_w2t(const float* __restrict__ W2, const float* __restrict__ b2,
                         const float* __restrict__ g2, const float* __restrict__ be2,
                         const float* __restrict__ m2, const float* __restrict__ v2,
                         unsigned short* __restrict__ W2T, float* __restrict__ fb2) {
  int t = blockIdx.x * blockDim.x + threadIdx.x;
  if (t >= 2 * 128 * 512) return;
  int k = t & 511, j = (t >> 9) & 127, m = t >> 16;
  float s = g2[m * 128 + j] * rsqrtf(v2[m * 128 + j] + 1e-5f);
  float val = (k < 500) ? W2[((size_t)m * 500 + k) * 128 + j] * s : 0.f;
  W2T[t] = f2bf(val);
  if (k == 0)
    fb2[m * 128 + j] = (b2[m * 128 + j] - m2[m * 128 + j]) * s + be2[m * 128 + j];
}

// Wd [2][128][64] -> WdT [128][256] (modality-concat K, pre-scaled 0.5); fbd [128]
__global__ void prep_wdt(const float* __restrict__ Wd, const float* __restrict__ bd,
                         unsigned short* __restrict__ WdT, float* __restrict__ fbd) {
  int t = blockIdx.x * blockDim.x + threadIdx.x;
  if (t >= 128 * 256) return;
  int kc = t & 255, d = t >> 8;
  float val = 0.f;
  if (d < 64) {
    int m = kc >> 7, k = kc & 127;
    val = 0.5f * Wd[((size_t)m * 128 + k) * 64 + d];
  }
  WdT[t] = f2bf(val);
  if (kc == 0) fbd[d] = (d < 64) ? 0.5f * (bd[d] + bd[64 + d]) : 0.f;
}

// ---------------- graph part ----------------
__global__ void zero_kernel(float* __restrict__ p, int n) {
  int i = blockIdx.x * blockDim.x + threadIdx.x;
  if (i < n) p[i] = 0.f;
}

__global__ void deg_kernel(const int* __restrict__ src, const int* __restrict__ dst,
                           float* __restrict__ dego, float* __restrict__ degi, int E) {
  int e = blockIdx.x * blockDim.x + threadIdx.x;
  if (e < E) {
    atomicAdd(&dego[src[e]], 1.0f);
    atomicAdd(&degi[dst[e]], 1.0f);
  }
}

__global__ void cscd_kernel(float* __restrict__ cs, float* __restrict__ cd, int N) {
  int n = blockIdx.x * blockDim.x + threadIdx.x;
  if (n < N) {
    cs[n] = rsqrtf(fmaxf(cs[n], 1.f));
    cd[n] = rsqrtf(fmaxf(cd[n], 1.f));
  }
}

// xw[n][j] = cs[n] * sum_k x[n][k]*W[k][j]
template <int DIN, int DOUT>
__global__ void xw_kernel(const float* __restrict__ x, int ldx, const float* __restrict__ W,
                          const float* __restrict__ cs, float* __restrict__ xw, int N) {
  __shared__ float Ws[DIN * DOUT];
  for (int i = threadIdx.x; i < DIN * DOUT; i += blockDim.x) Ws[i] = W[i];
  __syncthreads();
  int t = blockIdx.x * blockDim.x + threadIdx.x;
  int n = t / DOUT, j = t % DOUT;
  if (n >= N) return;
  const float* xr = x + (size_t)n * ldx;
  float acc = 0.f;
#pragma unroll
  for (int k = 0; k < DIN; k += 4) {
    f32x4 v = *(const f32x4*)(xr + k);
    acc += v[0] * Ws[k * DOUT + j] + v[1] * Ws[(k + 1) * DOUT + j] +
           v[2] * Ws[(k + 2) * DOUT + j] + v[3] * Ws[(k + 3) * DOUT + j];
  }
  xw[(size_t)n * DOUT + j] = acc * cs[n];
}

template <int DOUT>
__global__ void scatter_kernel(const int* __restrict__ src, const int* __restrict__ dst,
                               const float* __restrict__ xw, float* __restrict__ agg, int E) {
  constexpr int G = DOUT / 4 > 0 ? DOUT / 4 : 1;
  int t = blockIdx.x * blockDim.x + threadIdx.x;
  int e = t / G, g = t % G;
  if (e >= E) return;
  int s = src[e], d = dst[e];
  f32x4 v = *(const f32x4*)(xw + (size_t)s * DOUT + g * 4);
  float* o = agg + (size_t)d * DOUT + g * 4;
  atomicAdd(o + 0, v[0]);
  atomicAdd(o + 1, v[1]);
  atomicAdd(o + 2, v[2]);
  atomicAdd(o + 3, v[3]);
}

template <int DOUT, bool RELU>
__global__ void finalize_kernel(const float* __restrict__ agg, const float* __restrict__ cd,
                                const float* __restrict__ b, float* __restrict__ out, int N) {
  int t = blockIdx.x * blockDim.x + threadIdx.x;
  int n = t / DOUT, j = t % DOUT;
  if (n >= N) return;
  float v = agg[t] * cd[n] + b[j];
  out[t] = RELU ? fmaxf(v, 0.f) : v;
}

// ---------------- launcher ----------------
extern "C" void kernel_launch(void* const* d_in, const int* in_sizes, int n_in,
                              void* d_out, int out_size, void* d_ws, size_t ws_size,
                              hipStream_t stream) {
  const float* h = (const float*)d_in[0];
  const int* src = (const int*)d_in[1];
  const int* dst = (const int*)d_in[2];
  const float* W1 = (const float*)d_in[3];
  const float* b1 = (const float*)d_in[4];
  const float* g1 = (const float*)d_in[5];
  const float* be1 = (const float*)d_in[6];
  const float* m1 = (const float*)d_in[7];
  const float* v1 = (const float*)d_in[8];
  const float* W2 = (const float*)d_in[9];
  const float* b2 = (const float*)d_in[10];
  const float* g2 = (const float*)d_in[11];
  const float* be2 = (const float*)d_in[12];
  const float* m2 = (const float*)d_in[13];
  const float* v2 = (const float*)d_in[14];
  const float* Wd = (const float*)d_in[15];
  const float* bd = (const float*)d_in[16];
  const float* Wg0 = (const float*)d_in[17];
  const float* bg0 = (const float*)d_in[18];
  const float* Wg1 = (const float*)d_in[19];
  const float* bg1 = (const float*)d_in[20];
  const float* Wg2 = (const float*)d_in[21];
  const float* bg2 = (const float*)d_in[22];
  float* out = (float*)d_out;

  const int N = 50000, DIN = 2000;
  const int E = in_sizes[1];

  char* ws = (char*)d_ws;
  size_t off = 0;
  auto alloc = [&](size_t bytes) {
    void* p = ws + off;
    off = (off + bytes + 255) & ~(size_t)255;
    return p;
  };
  unsigned short* W1T = (unsigned short*)alloc(2ull * 512 * 2048 * 2);
  unsigned short* W2T = (unsigned short*)alloc(2ull * 128 * 512 * 2);
  unsigned short* WdT = (unsigned short*)alloc(128ull * 256 * 2);
  float* fb1 = (float*)alloc(2 * 512 * 4);
  float* fb2 = (float*)alloc(2 * 128 * 4);
  float* fbd = (float*)alloc(128 * 4);
  float* cs = (float*)alloc((size_t)N * 4);
  float* cd = (float*)alloc((size_t)N * 4);
  unsigned short* Z1 = (unsigned short*)alloc((size_t)N * 512 * 2);
  unsigned short* Z2 = (unsigned short*)alloc((size_t)N * 256 * 2);
  float* feat = (float*)alloc((size_t)N * 128 * 4);  // also reused for x1/x2
  float* xwb = (float*)alloc((size_t)N * 64 * 4);
  float* aggb = (float*)alloc((size_t)N * 64 * 4);
  float* x1 = feat;                    // feat dead after first xw pass
  float* x2 = feat + (size_t)N * 64;   // fits inside feat region (N*128 floats)

  // ---- weight prep ----
  prep_w1t<<<(2 * 512 * 2048 + 255) / 256, 256, 0, stream>>>(W1, b1, g1, be1, m1, v1, W1T, fb1);
  prep_w2t<<<(2 * 128 * 512 + 255) / 256, 256, 0, stream>>>(W2, b2, g2, be2, m2, v2, W2T, fb2);
  prep_wdt<<<(128 * 256 + 255) / 256, 256, 0, stream>>>(Wd, bd, WdT, fbd);

  // ---- degrees -> cs/cd ----
  zero_kernel<<<(2 * N + 255) / 256, 256, 0, stream>>>(cs, 2 * N);  // cs,cd contiguous
  deg_kernel<<<(E + 255) / 256, 256, 0, stream>>>(src, dst, cs, cd, E);
  cscd_kernel<<<(N + 255) / 256, 256, 0, stream>>>(cs, cd, N);

  // ---- encoder ----
  const int mt = (N + TBM - 1) / TBM;  // 391
  for (int m = 0; m < 2; m++) {
    gemm_kernel<false, true><<<dim3(mt, 4), 256, 0, stream>>>(
        h + (size_t)m * N * DIN, DIN, W1T + (size_t)m * 512 * 2048, 2048,
        fb1 + m * 512, Z1, 512, 0, N, DIN, 32);
    gemm_kernel<true, true><<<dim3(mt, 1), 256, 0, stream>>>(
        Z1, 512, W2T + (size_t)m * 128 * 512, 512, fb2 + m * 128, Z2, 256,
        m * 128, N, 512, 8);
  }
  gemm_kernel<true, false><<<dim3(mt, 1), 256, 0, stream>>>(
      Z2, 256, WdT, 256, fbd, feat, 128, 0, N, 256, 4);

  // ---- GraphConv 1: 64 -> 64, relu ----
  xw_kernel<64, 64><<<((size_t)N * 64 + 255) / 256, 256, 0, stream>>>(feat, 128, Wg0, cs, xwb, N);
  zero_kernel<<<((size_t)N * 64 + 255) / 256, 256, 0, stream>>>(aggb, N * 64);
  scatter_kernel<64><<<((size_t)E * 16 + 255) / 256, 256, 0, stream>>>(src, dst, xwb, aggb, E);
  finalize_kernel<64, true><<<((size_t)N * 64 + 255) / 256, 256, 0, stream>>>(aggb, cd, bg0, x1, N);

  // ---- GraphConv 2: 64 -> 32, relu ----
  xw_kernel<64, 32><<<((size_t)N * 32 + 255) / 256, 256, 0, stream>>>(x1, 64, Wg1, cs, xwb, N);
  zero_kernel<<<((size_t)N * 32 + 255) / 256, 256, 0, stream>>>(aggb, N * 32);
  scatter_kernel<32><<<((size_t)E * 8 + 255) / 256, 256, 0, stream>>>(src, dst, xwb, aggb, E);
  finalize_kernel<32, true><<<((size_t)N * 32 + 255) / 256, 256, 0, stream>>>(aggb, cd, bg1, x2, N);

  // ---- GraphConv 3: 32 -> 4, no relu, -> d_out ----
  xw_kernel<32, 4><<<((size_t)N * 4 + 255) / 256, 256, 0, stream>>>(x2, 32, Wg2, cs, xwb, N);
  zero_kernel<<<((size_t)N * 4 + 255) / 256, 256, 0, stream>>>(aggb, N * 4);
  scatter_kernel<4><<<((size_t)E + 255) / 256, 256, 0, stream>>>(src, dst, xwb, aggb, E);
  finalize_kernel<4, false><<<((size_t)N * 4 + 255) / 256, 256, 0, stream>>>(aggb, cd, bg2, out, N);
}